// Round 3
// baseline (240.383 us; speedup 1.0000x reference)
//
#include <hip/hip_runtime.h>

#define NPTS 12288
#define DIMS 8
#define EPS2 0.25f
#define MINS 5
#define NIB1 (NPTS / 256)      // 48
#define NW   (NPTS / 32)       // 384 words per adjacency row
#define SENT NPTS
#define RMAX 512               // max contracted labels (R~120 measured OK)
#define W    (RMAX / 32)       // 16 words per contracted-bitmap row
#define BIGL 0x3fffffff
#define FT   128               // threads for border kernel
#define FB   256               // threads for fillbm
#define FBGRID 256             // blocks for fillbm -> 1024 waves

// ---- k_adj geometry: column-ballot scheme ----
// 256 threads = 4 waves; each wave owns a 128-wide j strip held in registers
// (2 slots x 64 lanes). i-rows broadcast from LDS (3 ds_read per 128 pairs).
// Adjacency bits produced by __ballot (SALU); lane ii captures iteration ii's
// ballot words via cndmask select (no inline asm); rows flushed through an
// LDS transpose into coalesced 64B-per-row uint4 stores.
#define AIT 256                // i rows per block
#define AJT 512                // j columns per block
// grid: (NPTS/AIT = 48, NPTS/AJT = 24) = 1152 blocks x 4 waves

typedef float v2f __attribute__((ext_vector_type(2)));

// sum of squares, fmaf chain — SAME style for both LDS side and lane side so
// the adjacency predicate is exactly symmetric in (i,j).
__device__ __forceinline__ float sq8(const float4& a, const float4& b) {
  float sv = 0.f;
  sv = fmaf(a.x, a.x, sv); sv = fmaf(a.y, a.y, sv);
  sv = fmaf(a.z, a.z, sv); sv = fmaf(a.w, a.w, sv);
  sv = fmaf(b.x, b.x, sv); sv = fmaf(b.y, b.y, sv);
  sv = fmaf(b.z, b.z, sv); sv = fmaf(b.w, b.w, sv);
  return sv;
}

// ---------------- kernels ----------------

__global__ __launch_bounds__(256) void k_adj(const float* __restrict__ X,
                                             unsigned int* __restrict__ adj,
                                             int* __restrict__ density) {
  __shared__ float4 xsh[AIT][2];     // 8 KB: block's i-rows
  __shared__ float sqsh[AIT];        // 1 KB: sum of squares of i-rows
  __shared__ uint4 tr[2][4][64];     // 8 KB: double-buffered row-word transpose
  const int t = threadIdx.x;
  const int w = t >> 6, lane = t & 63;
  const int i0 = blockIdx.x * AIT;
  const int j0 = blockIdx.y * AJT;

  // stage i-rows + their squared norms
  {
    float4 a = ((const float4*)X)[(size_t)(i0 + t) * 2];
    float4 b = ((const float4*)X)[(size_t)(i0 + t) * 2 + 1];
    xsh[t][0] = a; xsh[t][1] = b;
    sqsh[t] = sq8(a, b);
  }

  // per-lane j points (2 slots per wave), held in registers for the whole block
  const int ja = j0 + w * 128 + lane;
  const int jb = ja + 64;
  v2f xja[4], xjb[4];
  float sqja, sqjb;
  {
    float4 a = ((const float4*)X)[(size_t)ja * 2];
    float4 b = ((const float4*)X)[(size_t)ja * 2 + 1];
    xja[0] = (v2f){a.x, a.y}; xja[1] = (v2f){a.z, a.w};
    xja[2] = (v2f){b.x, b.y}; xja[3] = (v2f){b.z, b.w};
    sqja = sq8(a, b);
  }
  {
    float4 a = ((const float4*)X)[(size_t)jb * 2];
    float4 b = ((const float4*)X)[(size_t)jb * 2 + 1];
    xjb[0] = (v2f){a.x, a.y}; xjb[1] = (v2f){a.z, a.w};
    xjb[2] = (v2f){b.x, b.y}; xjb[3] = (v2f){b.z, b.w};
    sqjb = sq8(a, b);
  }

  int dj0 = 0, dj1 = 0;              // per-lane column densities (symmetric)
  __syncthreads();

  for (int g = 0; g < AIT / 64; ++g) {
    unsigned int r0 = 0, r1 = 0, r2 = 0, r3 = 0;   // staged row words (lane ii)
#pragma unroll 16
    for (int ii = 0; ii < 64; ++ii) {
      int i = (g << 6) + ii;
      float4 A = xsh[i][0], B = xsh[i][1];         // broadcast ds_read_b128 x2
      float si = sqsh[i];                          // broadcast ds_read_b32
      // round-0-proven arithmetic: pk mul + 3 pk fma + hadd; (si+sj) - 2*dot
      v2f d0 = (v2f){A.x, A.y} * xja[0];
      d0 = __builtin_elementwise_fma((v2f){A.z, A.w}, xja[1], d0);
      d0 = __builtin_elementwise_fma((v2f){B.x, B.y}, xja[2], d0);
      d0 = __builtin_elementwise_fma((v2f){B.z, B.w}, xja[3], d0);
      v2f d1 = (v2f){A.x, A.y} * xjb[0];
      d1 = __builtin_elementwise_fma((v2f){A.z, A.w}, xjb[1], d1);
      d1 = __builtin_elementwise_fma((v2f){B.x, B.y}, xjb[2], d1);
      d1 = __builtin_elementwise_fma((v2f){B.z, B.w}, xjb[3], d1);
      float d20 = (si + sqja) - 2.0f * (d0.x + d0.y);
      float d21 = (si + sqjb) - 2.0f * (d1.x + d1.y);
      bool c0 = d20 <= EPS2;
      bool c1 = d21 <= EPS2;
      unsigned long long m0 = __ballot(c0);        // 64 j-bits of row i (slot0)
      unsigned long long m1 = __ballot(c1);        // slot1
      dj0 += c0; dj1 += c1;
      unsigned int m0lo = (unsigned int)m0, m0hi = (unsigned int)(m0 >> 32);
      unsigned int m1lo = (unsigned int)m1, m1hi = (unsigned int)(m1 >> 32);
      bool mine = (lane == ii);                    // 1 v_cmp + 4 v_cndmask
      r0 = mine ? m0lo : r0;
      r1 = mine ? m0hi : r1;
      r2 = mine ? m1lo : r2;
      r3 = mine ? m1hi : r3;
    }
    // lane ii now holds row (i0+g*64+ii)'s 4 words for this wave's j-quad;
    // write lane-sequential (conflict-free), read transposed for the flush.
    tr[g & 1][w][lane] = make_uint4(r0, r1, r2, r3);
    __syncthreads();
    // coalesced flush: 4 threads x 16B = full 64B line per row
    uint4 v = tr[g & 1][t & 3][t >> 2];
    *(uint4*)(adj + (size_t)(i0 + (g << 6) + (t >> 2)) * NW
              + blockIdx.y * 16 + (t & 3) * 4) = v;
  }
  atomicAdd(&density[ja], dj0);
  atomicAdd(&density[jb], dj1);
}

// corebm via ballot; block 0 zeroes the contracted bitmap
__global__ __launch_bounds__(256) void k_core(const int* __restrict__ density,
                                              unsigned long long* __restrict__ corebm,
                                              unsigned int* __restrict__ bm) {
  int t = threadIdx.x;
  if (blockIdx.x == 0) {
#pragma unroll
    for (int q = 0; q < RMAX * W / 256; q++) bm[t + q * 256] = 0u;
  }
  int i = blockIdx.x * 256 + t;
  unsigned long long m = __ballot(density[i] >= MINS);
  if ((t & 63) == 0) corebm[i >> 6] = m;
}

// hook[i] = min(i, first core neighbor with j < i)  (j > i can't lower the min)
__global__ __launch_bounds__(256) void k_hookbm(const unsigned int* __restrict__ adj,
                                                const unsigned int* __restrict__ cb32,
                                                int* __restrict__ hook) {
  __shared__ unsigned int cb[NW];
  int t = threadIdx.x;
  for (int w = t; w < NW; w += 256) cb[w] = cb32[w];
  __syncthreads();
  int i = blockIdx.x * 256 + t;
  const unsigned int* row = adj + (size_t)i * NW;
  int wi = i >> 5;
  int m = i;
  for (int w = 0; w <= wi; w++) {
    unsigned int x = row[w] & cb[w];
    if (w == wi) x &= (1u << (i & 31)) - 1;   // bits strictly below i
    if (x) { m = (w << 5) + __ffs(x) - 1; break; }  // first hit = min
  }
  hook[i] = m;
}

// root ranks in LDS + hook-chase (fused compress) + labL; 1024 threads.
__global__ __launch_bounds__(1024) void k_rid(const int* __restrict__ density,
                                              const int* __restrict__ hook,
                                              int* __restrict__ Rptr,
                                              int* __restrict__ labL,
                                              int* __restrict__ bcount) {
  __shared__ unsigned short ridS[NPTS];   // 24 KB: rank of each root index
  __shared__ int wsum[16];
  int t = threadIdx.x;
  int lane = t & 63, wid = t >> 6;
  const int SEG = NPTS / 1024;  // 12
  int base = t * SEG;
  int flags = 0;
  int s = 0;
#pragma unroll
  for (int k = 0; k < SEG; k++) {
    int i = base + k;
    int f = (density[i] >= MINS && hook[i] == i) ? 1 : 0;   // root test
    flags |= f << k;
    s += f;
  }
  int segsum = s;
#pragma unroll
  for (int off = 1; off < 64; off <<= 1) {
    int n = __shfl_up(s, off, 64);
    if (lane >= off) s += n;
  }
  if (lane == 63) wsum[wid] = s;
  __syncthreads();
  int woff = 0;
  for (int w = 0; w < wid; w++) woff += wsum[w];
  int run = woff + s - segsum;
#pragma unroll
  for (int k = 0; k < SEG; k++) {
    ridS[base + k] = (unsigned short)run;
    run += (flags >> k) & 1;
  }
  if (t == 1023) *Rptr = run;
  if (t == 0) *bcount = 0;
  __syncthreads();
  for (int k = 0; k < SEG; k++) {
    int i = base + k;
    int lab = -1;
    if (density[i] >= MINS) {
      int v = i, h = hook[v];                 // chase static forest (decreasing)
      while (h != v) { v = h; h = hook[v]; }
      lab = min((int)ridS[v], RMAX - 1);
    }
    labL[i] = lab;
  }
}

// crossing-label edges -> contracted adjacency. Wave-per-row, j>i only;
// labels from LDS; hot atomics in LDS; batched merge.
__global__ __launch_bounds__(FB) void k_fillbm(const unsigned int* __restrict__ adj,
                                               const unsigned int* __restrict__ cb32,
                                               const int* __restrict__ labL,
                                               unsigned int* __restrict__ bm) {
  __shared__ unsigned int bmL[RMAX * W];       // 32 KB private bitmap
  __shared__ unsigned short labS[NPTS];        // 24 KB labels (+1, 0 = non-core)
  __shared__ unsigned int cb[NW];              // 1.5 KB core bitmap
  int t = threadIdx.x;
  for (int q = t; q < RMAX * W; q += FB) bmL[q] = 0u;
  for (int q = t; q < NPTS; q += FB) labS[q] = (unsigned short)(labL[q] + 1);
  for (int w = t; w < NW; w += FB) cb[w] = cb32[w];
  __syncthreads();
  int lane = t & 63, wv = t >> 6;              // 4 waves per block
  int gw = blockIdx.x * 4 + wv;                // global wave id 0..1023
  for (int i = gw; i < NPTS; i += 4 * FBGRID) {
    int a0 = (int)labS[i] - 1;
    if (a0 < 0) continue;                      // wave-uniform
    const unsigned int* row = adj + (size_t)i * NW;
    int wi = i >> 5;
    for (int w = wi + lane; w < NW; w += 64) {
      unsigned int x = row[w] & cb[w];
      if (w == wi) x &= (0xFFFFFFFEu << (i & 31));   // bits strictly > i
      while (x) {
        int b = __ffs(x) - 1; x &= x - 1;
        int lj = (int)labS[(w << 5) + b] - 1;
        if (lj != a0) {
          atomicOr(&bmL[a0 * W + (lj >> 5)], 1u << (lj & 31));
          atomicOr(&bmL[lj * W + (a0 >> 5)], 1u << (a0 & 31));
        }
      }
    }
  }
  __syncthreads();
  for (int q = t; q < RMAX * W; q += FB) {
    unsigned int v = bmL[q];
    if (v) atomicOr(&bm[q], v);
  }
}

// connected components of the contracted graph (single block, LDS) + rank ids
__global__ __launch_bounds__(RMAX) void k_cc(const unsigned int* __restrict__ bm,
                                             const int* __restrict__ Rptr,
                                             int* __restrict__ clab) {
  __shared__ int lbl[RMAX];
  __shared__ int mn[RMAX];
  __shared__ int chg, cmp;
  int a = threadIdx.x;
  int R = *Rptr; if (R > RMAX) R = RMAX;
  lbl[a] = a;
  __syncthreads();
  while (true) {
    int m = lbl[a];
    if (a < R) {
      const unsigned int* row = bm + a * W;
#pragma unroll
      for (int w = 0; w < W; w++) {
        unsigned int bits = row[w];
        while (bits) {
          int b = __ffs(bits) - 1;
          bits &= bits - 1;
          m = min(m, lbl[(w << 5) + b]);
        }
      }
    }
    mn[a] = m;
    if (a == 0) chg = 0;
    __syncthreads();
    int l = lbl[a];
    if (m < l) { atomicMin(&lbl[l], m); atomicMin(&lbl[a], m); chg = 1; }
    __syncthreads();
    while (true) {
      if (a == 0) cmp = 0;
      __syncthreads();
      int nl = lbl[lbl[a]];
      __syncthreads();
      if (nl < lbl[a]) { lbl[a] = nl; cmp = 1; }
      __syncthreads();
      if (!cmp) break;
    }
    if (!chg) break;
    __syncthreads();
  }
  int flag = (a < R && lbl[a] == a) ? 1 : 0;
  mn[a] = flag;
  __syncthreads();
  for (int off = 1; off < RMAX; off <<= 1) {
    int v = mn[a];
    int add = (a >= off) ? mn[a - off] : 0;
    __syncthreads();
    mn[a] = v + add;
    __syncthreads();
  }
  clab[a] = mn[lbl[a]] - 1;
}

// per-point labels; collect border (non-core) points into a compact list
__global__ __launch_bounds__(256) void k_labels(const int* __restrict__ labL,
                                                const int* __restrict__ clab,
                                                int* __restrict__ labArr,
                                                int* __restrict__ blist,
                                                int* __restrict__ bcount,
                                                float* __restrict__ out) {
  int i = blockIdx.x * blockDim.x + threadIdx.x;
  if (i >= NPTS) return;
  int a = labL[i];
  if (a >= 0) {
    int lab = clab[a];
    labArr[i] = lab;
    out[i] = (float)lab;
  } else {
    labArr[i] = BIGL;
    out[i] = -1.0f;
    int pos = atomicAdd(bcount, 1);
    blist[pos] = i;
  }
}

// one block per border point: min cluster id over core neighbors (bitmap scan)
__global__ __launch_bounds__(FT) void k_border(const unsigned int* __restrict__ adj,
                                               const unsigned int* __restrict__ cb32,
                                               const int* __restrict__ labArr,
                                               const int* __restrict__ blist,
                                               const int* __restrict__ bcount,
                                               float* __restrict__ out) {
  __shared__ unsigned int cb[NW];
  __shared__ int wm[FT / 64];
  int t = threadIdx.x;
  for (int w = t; w < NW; w += FT) cb[w] = cb32[w];
  __syncthreads();
  int count = *bcount;
  for (int k = blockIdx.x; k < count; k += gridDim.x) {
    int p = blist[k];
    const unsigned int* row = adj + (size_t)p * NW;
    int m = BIGL;
    for (int w = t; w < NW; w += FT) {
      unsigned int x = row[w] & cb[w];
      while (x) {
        int b = __ffs(x) - 1; x &= x - 1;
        m = min(m, labArr[(w << 5) + b]);
      }
    }
#pragma unroll
    for (int off = 32; off >= 1; off >>= 1) m = min(m, __shfl_xor(m, off, 64));
    if ((t & 63) == 0) wm[t >> 6] = m;
    __syncthreads();
    if (t == 0) {
      int mm = min(wm[0], wm[1]);
      out[p] = (mm < BIGL) ? (float)mm : -1.0f;
    }
    __syncthreads();
  }
}

// ---------------- launch ----------------

extern "C" void kernel_launch(void* const* d_in, const int* in_sizes, int n_in,
                              void* d_out, int out_size, void* d_ws, size_t ws_size,
                              hipStream_t stream) {
  const float* X = (const float*)d_in[0];
  float* out = (float*)d_out;

  char* ws = (char*)d_ws;
  unsigned int* adj = (unsigned int*)ws;                     // 18,874,368 B
  size_t off = (size_t)NPTS * NW * 4;
  int* density = (int*)(ws + off);           off += 4 * NPTS;
  int* hook    = (int*)(ws + off);           off += 4 * NPTS;
  int* labL    = (int*)(ws + off);           off += 4 * NPTS;
  int* labArr  = (int*)(ws + off);           off += 4 * NPTS;
  int* blist   = (int*)(ws + off);           off += 4 * NPTS;
  unsigned long long* corebm = (unsigned long long*)(ws + off); off += 2048;
  unsigned int* bm  = (unsigned int*)(ws + off); off += 4 * RMAX * W;
  int* clab    = (int*)(ws + off);           off += 4 * RMAX;
  int* Rptr    = (int*)(ws + off);
  int* bcount  = Rptr + 1;

  hipMemsetAsync(density, 0, 4 * NPTS, stream);

  dim3 gridA(NPTS / AIT, NPTS / AJT);   // 48 x 24 = 1152 blocks x 4 waves

  k_adj<<<gridA, 256, 0, stream>>>(X, adj, density);
  k_core<<<NIB1, 256, 0, stream>>>(density, corebm, bm);
  k_hookbm<<<NIB1, 256, 0, stream>>>(adj, (const unsigned int*)corebm, hook);
  k_rid<<<1, 1024, 0, stream>>>(density, hook, Rptr, labL, bcount);
  k_fillbm<<<FBGRID, FB, 0, stream>>>(adj, (const unsigned int*)corebm, labL, bm);
  k_cc<<<1, RMAX, 0, stream>>>(bm, Rptr, clab);
  k_labels<<<NIB1, 256, 0, stream>>>(labL, clab, labArr, blist, bcount, out);
  k_border<<<256, FT, 0, stream>>>(adj, (const unsigned int*)corebm, labArr, blist, bcount, out);
}

// Round 4
// 217.145 us; speedup vs baseline: 1.1070x; 1.1070x over previous
//
#include <hip/hip_runtime.h>

#define NPTS 12288
#define DIMS 8
#define EPS2 0.25f
#define MINS 5
#define NIB1 (NPTS / 256)      // 48
#define NW   (NPTS / 32)       // 384 words per adjacency row
#define SENT NPTS
#define RMAX 512               // max contracted labels (R~120 measured OK)
#define W    (RMAX / 32)       // 16 words per contracted-bitmap row
#define BIGL 0x3fffffff
#define FT   128               // threads for border kernel
#define FB   256               // threads for fillbm
#define FBGRID 256             // blocks for fillbm -> 1024 waves

// k_adj geometry (round-0 proven inner loop): 256 thr x 2 rows = 512 rows/block;
// j-chunk 256 = 8 words. Triangular grid: only blocks with by >= 2*bx (600 of
// 1152). Lower-triangle tiles produced by in-block 32x32 bit transpose of the
// register-resident words (shfl butterfly), flushed via padded LDS, coalesced.
#define ATHR 256
#define AROWS 2
#define ATI  (ATHR * AROWS)    // 512 i-rows per block
#define AJC  256               // j columns per block
#define AWCH (AJC / 32)        // 8 words
#define NBLK 600               // sum_{bx=0}^{23} (48 - 2*bx)

typedef float v2f __attribute__((ext_vector_type(2)));

// packed-fp32 distance: 1 pk_mul + 3 pk_fma + hadd; same threshold semantics
__device__ __forceinline__ float dot8(const v2f* xi, const float4& a, const float4& b) {
  v2f y0 = {a.x, a.y}, y1 = {a.z, a.w}, y2 = {b.x, b.y}, y3 = {b.z, b.w};
  v2f d = xi[0] * y0;
  d = __builtin_elementwise_fma(xi[1], y1, d);
  d = __builtin_elementwise_fma(xi[2], y2, d);
  d = __builtin_elementwise_fma(xi[3], y3, d);
  return d.x + d.y;
}

// 32x32 bit-matrix transpose across a 32-lane group; lane l holds row l in/out.
// Stage s swaps row-index bit log2(s) with col-index bit log2(s); stages commute.
__device__ __forceinline__ unsigned int tr32(unsigned int x, int lane31) {
  const unsigned int M[5] = {0x0000FFFFu, 0x00FF00FFu, 0x0F0F0F0Fu,
                             0x33333333u, 0x55555555u};
  const int S[5] = {16, 8, 4, 2, 1};
#pragma unroll
  for (int k = 0; k < 5; ++k) {
    int s = S[k];
    unsigned int m = M[k];
    unsigned int p = __shfl_xor(x, s, 32);
    x = (lane31 & s) ? ((x & ~m) | ((p >> s) & m))
                     : ((x & m) | ((p & m) << s));
  }
  return x;
}

// ---------------- kernels ----------------

__global__ __launch_bounds__(ATHR) void k_adj(const float* __restrict__ X,
                                              unsigned int* __restrict__ adj,
                                              int* __restrict__ density) {
  __shared__ float4 xs[AJC][2];
  __shared__ float sqs[AJC];
  __shared__ unsigned int mir[256 * 17];   // 17 KB: padded mirror-row buffer
  int t = threadIdx.x;

  // triangular block id -> (bx, by): off(bx) = bx*(49-bx); by in [2bx, 48)
  int B = blockIdx.x;
  int bx = 0;
  while ((bx + 1) * (49 - (bx + 1)) <= B) bx++;
  int by = 2 * bx + (B - bx * (49 - bx));
  bool full = (by >= 2 * bx + 2);          // strictly above block-diagonal

  {
    int j = by * AJC + t;
    float4 a = ((const float4*)X)[j * 2];
    float4 b = ((const float4*)X)[j * 2 + 1];
    xs[t][0] = a; xs[t][1] = b;
    float sv = 0.f;
    sv = fmaf(a.x, a.x, sv); sv = fmaf(a.y, a.y, sv); sv = fmaf(a.z, a.z, sv); sv = fmaf(a.w, a.w, sv);
    sv = fmaf(b.x, b.x, sv); sv = fmaf(b.y, b.y, sv); sv = fmaf(b.z, b.z, sv); sv = fmaf(b.w, b.w, sv);
    sqs[t] = sv;
  }
  int i0 = bx * ATI + t, i1 = i0 + ATHR;
  v2f xi0[4], xi1[4];
  {
    float4 a0 = ((const float4*)X)[i0 * 2], b0v = ((const float4*)X)[i0 * 2 + 1];
    float4 a1 = ((const float4*)X)[i1 * 2], b1v = ((const float4*)X)[i1 * 2 + 1];
    xi0[0] = (v2f){a0.x, a0.y}; xi0[1] = (v2f){a0.z, a0.w};
    xi0[2] = (v2f){b0v.x, b0v.y}; xi0[3] = (v2f){b0v.z, b0v.w};
    xi1[0] = (v2f){a1.x, a1.y}; xi1[1] = (v2f){a1.z, a1.w};
    xi1[2] = (v2f){b1v.x, b1v.y}; xi1[3] = (v2f){b1v.z, b1v.w};
  }
  float sq0 = 0.f, sq1 = 0.f;
#pragma unroll
  for (int q = 0; q < 4; q++) {
    v2f p0 = xi0[q] * xi0[q], p1 = xi1[q] * xi1[q];
    sq0 += p0.x + p0.y; sq1 += p1.x + p1.y;
  }
  __syncthreads();
  unsigned int acc0[AWCH], acc1[AWCH];
#pragma unroll
  for (int w = 0; w < AWCH; w++) {   // unrolled: constant acc indices
    unsigned int b0 = 0u, b1 = 0u;
#pragma unroll 4
    for (int bit = 0; bit < 32; bit++) {
      int jj = (w << 5) + bit;
      float4 xa = xs[jj][0], xb = xs[jj][1];
      float sj = sqs[jj];
      unsigned int m = 1u << bit;
      float d20 = (sq0 + sj) - 2.0f * dot8(xi0, xa, xb);
      float d21 = (sq1 + sj) - 2.0f * dot8(xi1, xa, xb);
      if (d20 <= EPS2) b0 |= m;
      if (d21 <= EPS2) b1 |= m;
    }
    acc0[w] = b0; acc1[w] = b1;
  }

  // direct stores: words with tile-col (8*by+wl) >= tile-row (i>>5)
  if (full) {
    uint4* dst0 = (uint4*)(adj + (size_t)i0 * NW + by * AWCH);
    uint4* dst1 = (uint4*)(adj + (size_t)i1 * NW + by * AWCH);
    dst0[0] = make_uint4(acc0[0], acc0[1], acc0[2], acc0[3]);
    dst0[1] = make_uint4(acc0[4], acc0[5], acc0[6], acc0[7]);
    dst1[0] = make_uint4(acc1[0], acc1[1], acc1[2], acc1[3]);
    dst1[1] = make_uint4(acc1[4], acc1[5], acc1[6], acc1[7]);
    int pc0 = 0, pc1 = 0;
#pragma unroll
    for (int w = 0; w < AWCH; w++) { pc0 += __popc(acc0[w]); pc1 += __popc(acc1[w]); }
    atomicAdd(&density[i0], pc0);
    atomicAdd(&density[i1], pc1);
  } else {
    int lw0 = min(max((i0 >> 5) - 8 * by, 0), 8);
    int lw1 = min(max((i1 >> 5) - 8 * by, 0), 8);
    unsigned int* dst0 = adj + (size_t)i0 * NW + by * AWCH;
    unsigned int* dst1 = adj + (size_t)i1 * NW + by * AWCH;
    int pc0 = 0, pc1 = 0;
    for (int wl = lw0; wl < 8; wl++) { dst0[wl] = acc0[wl]; pc0 += __popc(acc0[wl]); }
    for (int wl = lw1; wl < 8; wl++) { dst1[wl] = acc1[wl]; pc1 += __popc(acc1[wl]); }
    if (lw0 < 8) atomicAdd(&density[i0], pc0);
    if (lw1 < 8) atomicAdd(&density[i1], pc1);
  }

  // mirror: transpose 32x32 tiles in-register, stage to padded LDS, flush.
  // dest rows = this block's j-chunk [256*by, +256); dest words = [16*bx, +16).
  const int lane31 = t & 31;
  const int hi = (t >> 5) & 1;
  const int wv = t >> 6;
#pragma unroll
  for (int wl = 0; wl < AWCH; ++wl) {
    unsigned int x0 = tr32(acc0[wl], lane31);
    unsigned int x1 = tr32(acc1[wl], lane31);
    int rr = (wl << 5) + lane31;               // dest row local (0..255)
    mir[rr * 17 + (wv << 1) + hi] = x0;        // dest word local 0..7  (i0 tiles)
    mir[rr * 17 + 8 + (wv << 1) + hi] = x1;    // dest word local 8..15 (i1 tiles)
  }
  __syncthreads();
  int rglob = by * 256 + t;
  const unsigned int* mrow = &mir[t * 17];
  unsigned int* dstm = adj + (size_t)rglob * NW + bx * 16;
  if (full) {                                   // all 16 words strictly lower
    ((uint4*)dstm)[0] = make_uint4(mrow[0], mrow[1], mrow[2], mrow[3]);
    ((uint4*)dstm)[1] = make_uint4(mrow[4], mrow[5], mrow[6], mrow[7]);
    ((uint4*)dstm)[2] = make_uint4(mrow[8], mrow[9], mrow[10], mrow[11]);
    ((uint4*)dstm)[3] = make_uint4(mrow[12], mrow[13], mrow[14], mrow[15]);
    int pc = 0;
#pragma unroll
    for (int q = 0; q < 16; q++) pc += __popc(mrow[q]);
    atomicAdd(&density[rglob], pc);
  } else {
    int nv = min(max((rglob >> 5) - 16 * bx, 0), 16);  // words strictly below diag tile
    int pc = 0;
    for (int q = 0; q < nv; q++) { dstm[q] = mrow[q]; pc += __popc(mrow[q]); }
    if (nv > 0) atomicAdd(&density[rglob], pc);
  }
}

// corebm via ballot; block 0 zeroes the contracted bitmap
__global__ __launch_bounds__(256) void k_core(const int* __restrict__ density,
                                              unsigned long long* __restrict__ corebm,
                                              unsigned int* __restrict__ bm) {
  int t = threadIdx.x;
  if (blockIdx.x == 0) {
#pragma unroll
    for (int q = 0; q < RMAX * W / 256; q++) bm[t + q * 256] = 0u;
  }
  int i = blockIdx.x * 256 + t;
  unsigned long long m = __ballot(density[i] >= MINS);
  if ((t & 63) == 0) corebm[i >> 6] = m;
}

// hook[i] = min(i, first core neighbor with j < i)  (j > i can't lower the min)
__global__ __launch_bounds__(256) void k_hookbm(const unsigned int* __restrict__ adj,
                                                const unsigned int* __restrict__ cb32,
                                                int* __restrict__ hook) {
  __shared__ unsigned int cb[NW];
  int t = threadIdx.x;
  for (int w = t; w < NW; w += 256) cb[w] = cb32[w];
  __syncthreads();
  int i = blockIdx.x * 256 + t;
  const unsigned int* row = adj + (size_t)i * NW;
  int wi = i >> 5;
  int m = i;
  for (int w = 0; w <= wi; w++) {
    unsigned int x = row[w] & cb[w];
    if (w == wi) x &= (1u << (i & 31)) - 1;   // bits strictly below i
    if (x) { m = (w << 5) + __ffs(x) - 1; break; }  // first hit = min
  }
  hook[i] = m;
}

// root ranks in LDS + hook-chase (fused compress) + labL; 1024 threads.
__global__ __launch_bounds__(1024) void k_rid(const int* __restrict__ density,
                                              const int* __restrict__ hook,
                                              int* __restrict__ Rptr,
                                              int* __restrict__ labL,
                                              int* __restrict__ bcount) {
  __shared__ unsigned short ridS[NPTS];   // 24 KB: rank of each root index
  __shared__ int wsum[16];
  int t = threadIdx.x;
  int lane = t & 63, wid = t >> 6;
  const int SEG = NPTS / 1024;  // 12
  int base = t * SEG;
  int flags = 0;
  int s = 0;
#pragma unroll
  for (int k = 0; k < SEG; k++) {
    int i = base + k;
    int f = (density[i] >= MINS && hook[i] == i) ? 1 : 0;   // root test
    flags |= f << k;
    s += f;
  }
  int segsum = s;
#pragma unroll
  for (int off = 1; off < 64; off <<= 1) {
    int n = __shfl_up(s, off, 64);
    if (lane >= off) s += n;
  }
  if (lane == 63) wsum[wid] = s;
  __syncthreads();
  int woff = 0;
  for (int w = 0; w < wid; w++) woff += wsum[w];
  int run = woff + s - segsum;
#pragma unroll
  for (int k = 0; k < SEG; k++) {
    ridS[base + k] = (unsigned short)run;
    run += (flags >> k) & 1;
  }
  if (t == 1023) *Rptr = run;
  if (t == 0) *bcount = 0;
  __syncthreads();
  for (int k = 0; k < SEG; k++) {
    int i = base + k;
    int lab = -1;
    if (density[i] >= MINS) {
      int v = i, h = hook[v];                 // chase static forest (decreasing)
      while (h != v) { v = h; h = hook[v]; }
      lab = min((int)ridS[v], RMAX - 1);
    }
    labL[i] = lab;
  }
}

// crossing-label edges -> contracted adjacency. Wave-per-row, j>i only;
// labels from LDS; hot atomics in LDS; batched merge.
__global__ __launch_bounds__(FB) void k_fillbm(const unsigned int* __restrict__ adj,
                                               const unsigned int* __restrict__ cb32,
                                               const int* __restrict__ labL,
                                               unsigned int* __restrict__ bm) {
  __shared__ unsigned int bmL[RMAX * W];       // 32 KB private bitmap
  __shared__ unsigned short labS[NPTS];        // 24 KB labels (+1, 0 = non-core)
  __shared__ unsigned int cb[NW];              // 1.5 KB core bitmap
  int t = threadIdx.x;
  for (int q = t; q < RMAX * W; q += FB) bmL[q] = 0u;
  for (int q = t; q < NPTS; q += FB) labS[q] = (unsigned short)(labL[q] + 1);
  for (int w = t; w < NW; w += FB) cb[w] = cb32[w];
  __syncthreads();
  int lane = t & 63, wv = t >> 6;              // 4 waves per block
  int gw = blockIdx.x * 4 + wv;                // global wave id 0..1023
  for (int i = gw; i < NPTS; i += 4 * FBGRID) {
    int a0 = (int)labS[i] - 1;
    if (a0 < 0) continue;                      // wave-uniform
    const unsigned int* row = adj + (size_t)i * NW;
    int wi = i >> 5;
    for (int w = wi + lane; w < NW; w += 64) {
      unsigned int x = row[w] & cb[w];
      if (w == wi) x &= (0xFFFFFFFEu << (i & 31));   // bits strictly > i
      while (x) {
        int b = __ffs(x) - 1; x &= x - 1;
        int lj = (int)labS[(w << 5) + b] - 1;
        if (lj != a0) {
          atomicOr(&bmL[a0 * W + (lj >> 5)], 1u << (lj & 31));
          atomicOr(&bmL[lj * W + (a0 >> 5)], 1u << (a0 & 31));
        }
      }
    }
  }
  __syncthreads();
  for (int q = t; q < RMAX * W; q += FB) {
    unsigned int v = bmL[q];
    if (v) atomicOr(&bm[q], v);
  }
}

// connected components of the contracted graph (single block, LDS) + rank ids
__global__ __launch_bounds__(RMAX) void k_cc(const unsigned int* __restrict__ bm,
                                             const int* __restrict__ Rptr,
                                             int* __restrict__ clab) {
  __shared__ int lbl[RMAX];
  __shared__ int mn[RMAX];
  __shared__ int chg, cmp;
  int a = threadIdx.x;
  int R = *Rptr; if (R > RMAX) R = RMAX;
  lbl[a] = a;
  __syncthreads();
  while (true) {
    int m = lbl[a];
    if (a < R) {
      const unsigned int* row = bm + a * W;
#pragma unroll
      for (int w = 0; w < W; w++) {
        unsigned int bits = row[w];
        while (bits) {
          int b = __ffs(bits) - 1;
          bits &= bits - 1;
          m = min(m, lbl[(w << 5) + b]);
        }
      }
    }
    mn[a] = m;
    if (a == 0) chg = 0;
    __syncthreads();
    int l = lbl[a];
    if (m < l) { atomicMin(&lbl[l], m); atomicMin(&lbl[a], m); chg = 1; }
    __syncthreads();
    while (true) {
      if (a == 0) cmp = 0;
      __syncthreads();
      int nl = lbl[lbl[a]];
      __syncthreads();
      if (nl < lbl[a]) { lbl[a] = nl; cmp = 1; }
      __syncthreads();
      if (!cmp) break;
    }
    if (!chg) break;
    __syncthreads();
  }
  int flag = (a < R && lbl[a] == a) ? 1 : 0;
  mn[a] = flag;
  __syncthreads();
  for (int off = 1; off < RMAX; off <<= 1) {
    int v = mn[a];
    int add = (a >= off) ? mn[a - off] : 0;
    __syncthreads();
    mn[a] = v + add;
    __syncthreads();
  }
  clab[a] = mn[lbl[a]] - 1;
}

// per-point labels; collect border (non-core) points into a compact list
__global__ __launch_bounds__(256) void k_labels(const int* __restrict__ labL,
                                                const int* __restrict__ clab,
                                                int* __restrict__ labArr,
                                                int* __restrict__ blist,
                                                int* __restrict__ bcount,
                                                float* __restrict__ out) {
  int i = blockIdx.x * blockDim.x + threadIdx.x;
  if (i >= NPTS) return;
  int a = labL[i];
  if (a >= 0) {
    int lab = clab[a];
    labArr[i] = lab;
    out[i] = (float)lab;
  } else {
    labArr[i] = BIGL;
    out[i] = -1.0f;
    int pos = atomicAdd(bcount, 1);
    blist[pos] = i;
  }
}

// one block per border point: min cluster id over core neighbors (bitmap scan)
__global__ __launch_bounds__(FT) void k_border(const unsigned int* __restrict__ adj,
                                               const unsigned int* __restrict__ cb32,
                                               const int* __restrict__ labArr,
                                               const int* __restrict__ blist,
                                               const int* __restrict__ bcount,
                                               float* __restrict__ out) {
  __shared__ unsigned int cb[NW];
  __shared__ int wm[FT / 64];
  int t = threadIdx.x;
  for (int w = t; w < NW; w += FT) cb[w] = cb32[w];
  __syncthreads();
  int count = *bcount;
  for (int k = blockIdx.x; k < count; k += gridDim.x) {
    int p = blist[k];
    const unsigned int* row = adj + (size_t)p * NW;
    int m = BIGL;
    for (int w = t; w < NW; w += FT) {
      unsigned int x = row[w] & cb[w];
      while (x) {
        int b = __ffs(x) - 1; x &= x - 1;
        m = min(m, labArr[(w << 5) + b]);
      }
    }
#pragma unroll
    for (int off = 32; off >= 1; off >>= 1) m = min(m, __shfl_xor(m, off, 64));
    if ((t & 63) == 0) wm[t >> 6] = m;
    __syncthreads();
    if (t == 0) {
      int mm = min(wm[0], wm[1]);
      out[p] = (mm < BIGL) ? (float)mm : -1.0f;
    }
    __syncthreads();
  }
}

// ---------------- launch ----------------

extern "C" void kernel_launch(void* const* d_in, const int* in_sizes, int n_in,
                              void* d_out, int out_size, void* d_ws, size_t ws_size,
                              hipStream_t stream) {
  const float* X = (const float*)d_in[0];
  float* out = (float*)d_out;

  char* ws = (char*)d_ws;
  unsigned int* adj = (unsigned int*)ws;                     // 18,874,368 B
  size_t off = (size_t)NPTS * NW * 4;
  int* density = (int*)(ws + off);           off += 4 * NPTS;
  int* hook    = (int*)(ws + off);           off += 4 * NPTS;
  int* labL    = (int*)(ws + off);           off += 4 * NPTS;
  int* labArr  = (int*)(ws + off);           off += 4 * NPTS;
  int* blist   = (int*)(ws + off);           off += 4 * NPTS;
  unsigned long long* corebm = (unsigned long long*)(ws + off); off += 2048;
  unsigned int* bm  = (unsigned int*)(ws + off); off += 4 * RMAX * W;
  int* clab    = (int*)(ws + off);           off += 4 * RMAX;
  int* Rptr    = (int*)(ws + off);
  int* bcount  = Rptr + 1;

  hipMemsetAsync(density, 0, 4 * NPTS, stream);

  k_adj<<<NBLK, ATHR, 0, stream>>>(X, adj, density);
  k_core<<<NIB1, 256, 0, stream>>>(density, corebm, bm);
  k_hookbm<<<NIB1, 256, 0, stream>>>(adj, (const unsigned int*)corebm, hook);
  k_rid<<<1, 1024, 0, stream>>>(density, hook, Rptr, labL, bcount);
  k_fillbm<<<FBGRID, FB, 0, stream>>>(adj, (const unsigned int*)corebm, labL, bm);
  k_cc<<<1, RMAX, 0, stream>>>(bm, Rptr, clab);
  k_labels<<<NIB1, 256, 0, stream>>>(labL, clab, labArr, blist, bcount, out);
  k_border<<<256, FT, 0, stream>>>(adj, (const unsigned int*)corebm, labArr, blist, bcount, out);
}

// Round 5
// 207.281 us; speedup vs baseline: 1.1597x; 1.0476x over previous
//
#include <hip/hip_runtime.h>

#define NPTS 12288
#define DIMS 8
#define EPS2 0.25f
#define MINS 5
#define NIB1 (NPTS / 256)      // 48
#define NW   (NPTS / 32)       // 384 words per adjacency row
#define SENT NPTS
#define RMAX 512               // max contracted labels (R~120 measured OK)
#define W    (RMAX / 32)       // 16 words per contracted-bitmap row
#define BIGL 0x3fffffff
#define FT   128               // threads for border kernel
#define FB   256               // threads for fillbm
#define FBGRID 256             // blocks for fillbm -> 1024 waves

// k_adj geometry: 256 thr x 2 rows = 512 rows/block; j-chunk 128 = 4 words.
// Triangular: chunks with by >= 4*bx (1200 blocks = 4.69/CU, ~19 waves/CU).
// Lower triangle via in-register 32x32 bit transpose + padded LDS flush.
#define ATHR 256
#define AROWS 2
#define ATI  (ATHR * AROWS)    // 512 i-rows per block
#define AJC  128               // j columns per block
#define AWCH (AJC / 32)        // 4 words
#define NJC  (NPTS / AJC)      // 96 j-chunks
#define NBLK 1200              // sum_{bx=0}^{23} (96 - 4*bx)

typedef float v2f __attribute__((ext_vector_type(2)));

// packed-fp32 distance: 1 pk_mul + 3 pk_fma + hadd; same threshold semantics
__device__ __forceinline__ float dot8(const v2f* xi, const float4& a, const float4& b) {
  v2f y0 = {a.x, a.y}, y1 = {a.z, a.w}, y2 = {b.x, b.y}, y3 = {b.z, b.w};
  v2f d = xi[0] * y0;
  d = __builtin_elementwise_fma(xi[1], y1, d);
  d = __builtin_elementwise_fma(xi[2], y2, d);
  d = __builtin_elementwise_fma(xi[3], y3, d);
  return d.x + d.y;
}

// 32x32 bit-matrix transpose across a 32-lane group; lane l holds row l in/out.
__device__ __forceinline__ unsigned int tr32(unsigned int x, int lane31) {
  const unsigned int M[5] = {0x0000FFFFu, 0x00FF00FFu, 0x0F0F0F0Fu,
                             0x33333333u, 0x55555555u};
  const int S[5] = {16, 8, 4, 2, 1};
#pragma unroll
  for (int k = 0; k < 5; ++k) {
    int s = S[k];
    unsigned int m = M[k];
    unsigned int p = __shfl_xor(x, s, 32);
    x = (lane31 & s) ? ((x & ~m) | ((p >> s) & m))
                     : ((x & m) | ((p & m) << s));
  }
  return x;
}

// ---------------- kernels ----------------

__global__ __launch_bounds__(ATHR) void k_adj(const float* __restrict__ X,
                                              unsigned int* __restrict__ adj,
                                              int* __restrict__ density) {
  __shared__ float4 xs[AJC][2];            // 4 KB
  __shared__ float sqs[AJC];               // 0.5 KB
  __shared__ unsigned int mir[AJC * 17];   // 8.7 KB padded mirror buffer
  int t = threadIdx.x;

  // triangular block id -> (bx, by): off(bx) = 2*bx*(49-bx); by in [4bx, 96)
  int B = blockIdx.x;
  int bx = 0;
  while (2 * (bx + 1) * (48 - bx) <= B) bx++;
  int by = 4 * bx + (B - 2 * bx * (49 - bx));
  bool full = (by >= 4 * bx + 4);          // strictly above the diagonal band

  if (t < AJC) {
    int j = by * AJC + t;
    float4 a = ((const float4*)X)[j * 2];
    float4 b = ((const float4*)X)[j * 2 + 1];
    xs[t][0] = a; xs[t][1] = b;
    float sv = 0.f;
    sv = fmaf(a.x, a.x, sv); sv = fmaf(a.y, a.y, sv); sv = fmaf(a.z, a.z, sv); sv = fmaf(a.w, a.w, sv);
    sv = fmaf(b.x, b.x, sv); sv = fmaf(b.y, b.y, sv); sv = fmaf(b.z, b.z, sv); sv = fmaf(b.w, b.w, sv);
    sqs[t] = sv;
  }
  int i0 = bx * ATI + t, i1 = i0 + ATHR;
  v2f xi0[4], xi1[4];
  {
    float4 a0 = ((const float4*)X)[i0 * 2], b0v = ((const float4*)X)[i0 * 2 + 1];
    float4 a1 = ((const float4*)X)[i1 * 2], b1v = ((const float4*)X)[i1 * 2 + 1];
    xi0[0] = (v2f){a0.x, a0.y}; xi0[1] = (v2f){a0.z, a0.w};
    xi0[2] = (v2f){b0v.x, b0v.y}; xi0[3] = (v2f){b0v.z, b0v.w};
    xi1[0] = (v2f){a1.x, a1.y}; xi1[1] = (v2f){a1.z, a1.w};
    xi1[2] = (v2f){b1v.x, b1v.y}; xi1[3] = (v2f){b1v.z, b1v.w};
  }
  float sq0 = 0.f, sq1 = 0.f;
#pragma unroll
  for (int q = 0; q < 4; q++) {
    v2f p0 = xi0[q] * xi0[q], p1 = xi1[q] * xi1[q];
    sq0 += p0.x + p0.y; sq1 += p1.x + p1.y;
  }
  __syncthreads();
  unsigned int acc0[AWCH], acc1[AWCH];
#pragma unroll
  for (int w = 0; w < AWCH; w++) {   // unrolled: constant acc indices
    unsigned int b0 = 0u, b1 = 0u;
#pragma unroll 4
    for (int bit = 0; bit < 32; bit++) {
      int jj = (w << 5) + bit;
      float4 xa = xs[jj][0], xb = xs[jj][1];
      float sj = sqs[jj];
      unsigned int m = 1u << bit;
      float d20 = (sq0 + sj) - 2.0f * dot8(xi0, xa, xb);
      float d21 = (sq1 + sj) - 2.0f * dot8(xi1, xa, xb);
      if (d20 <= EPS2) b0 |= m;
      if (d21 <= EPS2) b1 |= m;
    }
    acc0[w] = b0; acc1[w] = b1;
  }

  // direct stores: words with tile-col (4*by+wl) >= tile-row (i>>5)
  if (full) {
    *(uint4*)(adj + (size_t)i0 * NW + by * AWCH) = make_uint4(acc0[0], acc0[1], acc0[2], acc0[3]);
    *(uint4*)(adj + (size_t)i1 * NW + by * AWCH) = make_uint4(acc1[0], acc1[1], acc1[2], acc1[3]);
    int pc0 = 0, pc1 = 0;
#pragma unroll
    for (int w = 0; w < AWCH; w++) { pc0 += __popc(acc0[w]); pc1 += __popc(acc1[w]); }
    atomicAdd(&density[i0], pc0);
    atomicAdd(&density[i1], pc1);
  } else {
    int lw0 = min(max((i0 >> 5) - 4 * by, 0), 4);
    int lw1 = min(max((i1 >> 5) - 4 * by, 0), 4);
    unsigned int* dst0 = adj + (size_t)i0 * NW + by * AWCH;
    unsigned int* dst1 = adj + (size_t)i1 * NW + by * AWCH;
    int pc0 = 0, pc1 = 0;
    for (int wl = lw0; wl < AWCH; wl++) { dst0[wl] = acc0[wl]; pc0 += __popc(acc0[wl]); }
    for (int wl = lw1; wl < AWCH; wl++) { dst1[wl] = acc1[wl]; pc1 += __popc(acc1[wl]); }
    if (lw0 < AWCH) atomicAdd(&density[i0], pc0);
    if (lw1 < AWCH) atomicAdd(&density[i1], pc1);
  }

  // mirror: transpose 32x32 tiles in-register, stage to padded LDS, flush.
  // dest rows = this block's j-chunk [128*by, +128); dest words = [16*bx, +16).
  const int lane31 = t & 31;
  const int g = t >> 5;                    // source 32-row group (0..7)
#pragma unroll
  for (int wl = 0; wl < AWCH; ++wl) {
    unsigned int x0 = tr32(acc0[wl], lane31);
    unsigned int x1 = tr32(acc1[wl], lane31);
    int rr = (wl << 5) + lane31;           // dest row local (0..127)
    mir[rr * 17 + g] = x0;                 // dest word local 0..7  (i0 rows)
    mir[rr * 17 + 8 + g] = x1;             // dest word local 8..15 (i1 rows)
  }
  __syncthreads();
  {
    int r = t >> 1, half = t & 1;          // 2 threads per dest row
    int rglob = by * AJC + r;
    const unsigned int* mrow = &mir[r * 17 + half * 8];
    unsigned int* dstm = adj + (size_t)rglob * NW + bx * 16 + half * 8;
    if (full) {                            // all 16 words strictly lower
      ((uint4*)dstm)[0] = make_uint4(mrow[0], mrow[1], mrow[2], mrow[3]);
      ((uint4*)dstm)[1] = make_uint4(mrow[4], mrow[5], mrow[6], mrow[7]);
      int pc = 0;
#pragma unroll
      for (int q = 0; q < 8; q++) pc += __popc(mrow[q]);
      atomicAdd(&density[rglob], pc);
    } else {
      int nv = min(max((rglob >> 5) - 16 * bx, 0), 16);  // words strictly below diag tile
      int pc = 0, st = 0;
      for (int q = 0; q < 8; q++) {
        int qg = half * 8 + q;
        if (qg < nv) { dstm[q] = mrow[q]; pc += __popc(mrow[q]); st = 1; }
      }
      if (st) atomicAdd(&density[rglob], pc);
    }
  }
}

// corebm via ballot; block 0 zeroes the contracted bitmap
__global__ __launch_bounds__(256) void k_core(const int* __restrict__ density,
                                              unsigned long long* __restrict__ corebm,
                                              unsigned int* __restrict__ bm) {
  int t = threadIdx.x;
  if (blockIdx.x == 0) {
#pragma unroll
    for (int q = 0; q < RMAX * W / 256; q++) bm[t + q * 256] = 0u;
  }
  int i = blockIdx.x * 256 + t;
  unsigned long long m = __ballot(density[i] >= MINS);
  if ((t & 63) == 0) corebm[i >> 6] = m;
}

// hook[i] = min(i, first core neighbor with j < i); 192 blocks x 64 for spread
__global__ __launch_bounds__(64) void k_hookbm(const unsigned int* __restrict__ adj,
                                               const unsigned int* __restrict__ cb32,
                                               int* __restrict__ hook) {
  __shared__ unsigned int cb[NW];
  int t = threadIdx.x;
  for (int w = t; w < NW; w += 64) cb[w] = cb32[w];
  __syncthreads();
  int i = blockIdx.x * 64 + t;
  const unsigned int* row = adj + (size_t)i * NW;
  int wi = i >> 5;
  int m = i;
  for (int w = 0; w <= wi; w++) {
    unsigned int x = row[w] & cb[w];
    if (w == wi) x &= (1u << (i & 31)) - 1;   // bits strictly below i
    if (x) { m = (w << 5) + __ffs(x) - 1; break; }  // first hit = min
  }
  hook[i] = m;
}

// root ranks in LDS + hook-chase (fused compress) + labL; 1024 threads.
__global__ __launch_bounds__(1024) void k_rid(const int* __restrict__ density,
                                              const int* __restrict__ hook,
                                              int* __restrict__ Rptr,
                                              int* __restrict__ labL,
                                              int* __restrict__ bcount) {
  __shared__ unsigned short ridS[NPTS];   // 24 KB: rank of each root index
  __shared__ int wsum[16];
  int t = threadIdx.x;
  int lane = t & 63, wid = t >> 6;
  const int SEG = NPTS / 1024;  // 12
  int base = t * SEG;
  int flags = 0;
  int s = 0;
#pragma unroll
  for (int k = 0; k < SEG; k++) {
    int i = base + k;
    int f = (density[i] >= MINS && hook[i] == i) ? 1 : 0;   // root test
    flags |= f << k;
    s += f;
  }
  int segsum = s;
#pragma unroll
  for (int off = 1; off < 64; off <<= 1) {
    int n = __shfl_up(s, off, 64);
    if (lane >= off) s += n;
  }
  if (lane == 63) wsum[wid] = s;
  __syncthreads();
  int woff = 0;
  for (int w = 0; w < wid; w++) woff += wsum[w];
  int run = woff + s - segsum;
#pragma unroll
  for (int k = 0; k < SEG; k++) {
    ridS[base + k] = (unsigned short)run;
    run += (flags >> k) & 1;
  }
  if (t == 1023) *Rptr = run;
  if (t == 0) *bcount = 0;
  __syncthreads();
  for (int k = 0; k < SEG; k++) {
    int i = base + k;
    int lab = -1;
    if (density[i] >= MINS) {
      int v = i, h = hook[v];                 // chase static forest (decreasing)
      while (h != v) { v = h; h = hook[v]; }
      lab = min((int)ridS[v], RMAX - 1);
    }
    labL[i] = lab;
  }
}

// crossing-label edges -> contracted adjacency. Wave-per-row, j>i only;
// labels from LDS; hot atomics in LDS; batched merge.
__global__ __launch_bounds__(FB) void k_fillbm(const unsigned int* __restrict__ adj,
                                               const unsigned int* __restrict__ cb32,
                                               const int* __restrict__ labL,
                                               unsigned int* __restrict__ bm) {
  __shared__ unsigned int bmL[RMAX * W];       // 32 KB private bitmap
  __shared__ unsigned short labS[NPTS];        // 24 KB labels (+1, 0 = non-core)
  __shared__ unsigned int cb[NW];              // 1.5 KB core bitmap
  int t = threadIdx.x;
  for (int q = t; q < RMAX * W; q += FB) bmL[q] = 0u;
  for (int q = t; q < NPTS; q += FB) labS[q] = (unsigned short)(labL[q] + 1);
  for (int w = t; w < NW; w += FB) cb[w] = cb32[w];
  __syncthreads();
  int lane = t & 63, wv = t >> 6;              // 4 waves per block
  int gw = blockIdx.x * 4 + wv;                // global wave id 0..1023
  for (int i = gw; i < NPTS; i += 4 * FBGRID) {
    int a0 = (int)labS[i] - 1;
    if (a0 < 0) continue;                      // wave-uniform
    const unsigned int* row = adj + (size_t)i * NW;
    int wi = i >> 5;
    for (int w = wi + lane; w < NW; w += 64) {
      unsigned int x = row[w] & cb[w];
      if (w == wi) x &= (0xFFFFFFFEu << (i & 31));   // bits strictly > i
      while (x) {
        int b = __ffs(x) - 1; x &= x - 1;
        int lj = (int)labS[(w << 5) + b] - 1;
        if (lj != a0) {
          atomicOr(&bmL[a0 * W + (lj >> 5)], 1u << (lj & 31));
          atomicOr(&bmL[lj * W + (a0 >> 5)], 1u << (a0 & 31));
        }
      }
    }
  }
  __syncthreads();
  for (int q = t; q < RMAX * W; q += FB) {
    unsigned int v = bmL[q];
    if (v) atomicOr(&bm[q], v);
  }
}

// connected components of the contracted graph (single block, LDS) + rank ids
__global__ __launch_bounds__(RMAX) void k_cc(const unsigned int* __restrict__ bm,
                                             const int* __restrict__ Rptr,
                                             int* __restrict__ clab) {
  __shared__ int lbl[RMAX];
  __shared__ int mn[RMAX];
  __shared__ int chg, cmp;
  int a = threadIdx.x;
  int R = *Rptr; if (R > RMAX) R = RMAX;
  lbl[a] = a;
  __syncthreads();
  while (true) {
    int m = lbl[a];
    if (a < R) {
      const unsigned int* row = bm + a * W;
#pragma unroll
      for (int w = 0; w < W; w++) {
        unsigned int bits = row[w];
        while (bits) {
          int b = __ffs(bits) - 1;
          bits &= bits - 1;
          m = min(m, lbl[(w << 5) + b]);
        }
      }
    }
    mn[a] = m;
    if (a == 0) chg = 0;
    __syncthreads();
    int l = lbl[a];
    if (m < l) { atomicMin(&lbl[l], m); atomicMin(&lbl[a], m); chg = 1; }
    __syncthreads();
    while (true) {
      if (a == 0) cmp = 0;
      __syncthreads();
      int nl = lbl[lbl[a]];
      __syncthreads();
      if (nl < lbl[a]) { lbl[a] = nl; cmp = 1; }
      __syncthreads();
      if (!cmp) break;
    }
    if (!chg) break;
    __syncthreads();
  }
  int flag = (a < R && lbl[a] == a) ? 1 : 0;
  mn[a] = flag;
  __syncthreads();
  for (int off = 1; off < RMAX; off <<= 1) {
    int v = mn[a];
    int add = (a >= off) ? mn[a - off] : 0;
    __syncthreads();
    mn[a] = v + add;
    __syncthreads();
  }
  clab[a] = mn[lbl[a]] - 1;
}

// per-point labels; collect border (non-core) points into a compact list
__global__ __launch_bounds__(256) void k_labels(const int* __restrict__ labL,
                                                const int* __restrict__ clab,
                                                int* __restrict__ labArr,
                                                int* __restrict__ blist,
                                                int* __restrict__ bcount,
                                                float* __restrict__ out) {
  int i = blockIdx.x * blockDim.x + threadIdx.x;
  if (i >= NPTS) return;
  int a = labL[i];
  if (a >= 0) {
    int lab = clab[a];
    labArr[i] = lab;
    out[i] = (float)lab;
  } else {
    labArr[i] = BIGL;
    out[i] = -1.0f;
    int pos = atomicAdd(bcount, 1);
    blist[pos] = i;
  }
}

// one block per border point: min cluster id over core neighbors (bitmap scan)
__global__ __launch_bounds__(FT) void k_border(const unsigned int* __restrict__ adj,
                                               const unsigned int* __restrict__ cb32,
                                               const int* __restrict__ labArr,
                                               const int* __restrict__ blist,
                                               const int* __restrict__ bcount,
                                               float* __restrict__ out) {
  __shared__ unsigned int cb[NW];
  __shared__ int wm[FT / 64];
  int t = threadIdx.x;
  for (int w = t; w < NW; w += FT) cb[w] = cb32[w];
  __syncthreads();
  int count = *bcount;
  for (int k = blockIdx.x; k < count; k += gridDim.x) {
    int p = blist[k];
    const unsigned int* row = adj + (size_t)p * NW;
    int m = BIGL;
    for (int w = t; w < NW; w += FT) {
      unsigned int x = row[w] & cb[w];
      while (x) {
        int b = __ffs(x) - 1; x &= x - 1;
        m = min(m, labArr[(w << 5) + b]);
      }
    }
#pragma unroll
    for (int off = 32; off >= 1; off >>= 1) m = min(m, __shfl_xor(m, off, 64));
    if ((t & 63) == 0) wm[t >> 6] = m;
    __syncthreads();
    if (t == 0) {
      int mm = min(wm[0], wm[1]);
      out[p] = (mm < BIGL) ? (float)mm : -1.0f;
    }
    __syncthreads();
  }
}

// ---------------- launch ----------------

extern "C" void kernel_launch(void* const* d_in, const int* in_sizes, int n_in,
                              void* d_out, int out_size, void* d_ws, size_t ws_size,
                              hipStream_t stream) {
  const float* X = (const float*)d_in[0];
  float* out = (float*)d_out;

  char* ws = (char*)d_ws;
  unsigned int* adj = (unsigned int*)ws;                     // 18,874,368 B
  size_t off = (size_t)NPTS * NW * 4;
  int* density = (int*)(ws + off);           off += 4 * NPTS;
  int* hook    = (int*)(ws + off);           off += 4 * NPTS;
  int* labL    = (int*)(ws + off);           off += 4 * NPTS;
  int* labArr  = (int*)(ws + off);           off += 4 * NPTS;
  int* blist   = (int*)(ws + off);           off += 4 * NPTS;
  unsigned long long* corebm = (unsigned long long*)(ws + off); off += 2048;
  unsigned int* bm  = (unsigned int*)(ws + off); off += 4 * RMAX * W;
  int* clab    = (int*)(ws + off);           off += 4 * RMAX;
  int* Rptr    = (int*)(ws + off);
  int* bcount  = Rptr + 1;

  hipMemsetAsync(density, 0, 4 * NPTS, stream);

  k_adj<<<NBLK, ATHR, 0, stream>>>(X, adj, density);
  k_core<<<NIB1, 256, 0, stream>>>(density, corebm, bm);
  k_hookbm<<<NPTS / 64, 64, 0, stream>>>(adj, (const unsigned int*)corebm, hook);
  k_rid<<<1, 1024, 0, stream>>>(density, hook, Rptr, labL, bcount);
  k_fillbm<<<FBGRID, FB, 0, stream>>>(adj, (const unsigned int*)corebm, labL, bm);
  k_cc<<<1, RMAX, 0, stream>>>(bm, Rptr, clab);
  k_labels<<<NIB1, 256, 0, stream>>>(labL, clab, labArr, blist, bcount, out);
  k_border<<<256, FT, 0, stream>>>(adj, (const unsigned int*)corebm, labArr, blist, bcount, out);
}